// Round 1
// baseline (233.160 us; speedup 1.0000x reference)
//
#include <hip/hip_runtime.h>
#include <math.h>

#define NT 512      // threads per block (8 waves)
#define DL 128      // latent dim
#define TSEG 1024   // T / SLOTS = 8192 / 8

// Block-wide sum over all NT threads (inactive threads pass 0).
// Returns the total to every thread. Uses wave shuffles + LDS combine.
__device__ __forceinline__ float blocksum(float x, float* sc, int tid) {
#pragma unroll
    for (int o = 1; o < 64; o <<= 1) x += __shfl_xor(x, o, 64);
    __syncthreads();                 // protect sc from previous use (WAR)
    if ((tid & 63) == 0) sc[tid >> 6] = x;
    __syncthreads();
    float s = 0.f;
#pragma unroll
    for (int w = 0; w < NT / 64; ++w) s += sc[w];
    return s;
}

extern "C" __global__ void __launch_bounds__(NT)
ckv_fused(const float* __restrict__ k_lat, const float* __restrict__ v_lat,
          const float* __restrict__ wg_ln_g, const float* __restrict__ wg_ln_b,
          const float* __restrict__ wg_w,    const float* __restrict__ wg_b,
          const float* __restrict__ rh_ln_g, const float* __restrict__ rh_ln_b,
          const float* __restrict__ rh_w,    const float* __restrict__ rh_b,
          const float* __restrict__ pk_ln_g, const float* __restrict__ pk_ln_b,
          const float* __restrict__ pk_w,
          const float* __restrict__ pv_ln_g, const float* __restrict__ pv_ln_b,
          const float* __restrict__ pv_w,
          float* __restrict__ out, long long vout_off)
{
    __shared__ float red[NT][4];
    __shared__ float mk[DL], mv[DL], lnk[DL], lnv[DL];
    __shared__ float sc[NT / 64];

    const int tid = threadIdx.x;
    const int seg = blockIdx.x;                       // 0 .. B*H*SLOTS-1
    // segment rows are globally contiguous: row range [seg*TSEG, (seg+1)*TSEG)
    const long long base4 = (long long)seg * (TSEG * DL / 4);  // in float4 units

    const int col4 = tid & 31;   // float4 column within a 128-float row
    const int rl   = tid >> 5;   // row lane 0..15

    // ---------------- pool k ----------------
    {
        const float4* kp = (const float4*)k_lat + base4;
        float4 a = make_float4(0.f, 0.f, 0.f, 0.f);
        for (int t = rl; t < TSEG; t += 16) {
            float4 x = kp[t * 32 + col4];
            a.x += x.x; a.y += x.y; a.z += x.z; a.w += x.w;
        }
        red[tid][0] = a.x; red[tid][1] = a.y; red[tid][2] = a.z; red[tid][3] = a.w;
    }
    __syncthreads();
    if (tid < 32) {
        float s0 = 0.f, s1 = 0.f, s2 = 0.f, s3 = 0.f;
#pragma unroll
        for (int r = 0; r < 16; ++r) {
            s0 += red[r * 32 + tid][0]; s1 += red[r * 32 + tid][1];
            s2 += red[r * 32 + tid][2]; s3 += red[r * 32 + tid][3];
        }
        const float inv = 1.0f / (float)TSEG;
        mk[tid * 4 + 0] = s0 * inv; mk[tid * 4 + 1] = s1 * inv;
        mk[tid * 4 + 2] = s2 * inv; mk[tid * 4 + 3] = s3 * inv;
    }
    __syncthreads();

    // ---------------- pool v ----------------
    {
        const float4* vp = (const float4*)v_lat + base4;
        float4 a = make_float4(0.f, 0.f, 0.f, 0.f);
        for (int t = rl; t < TSEG; t += 16) {
            float4 x = vp[t * 32 + col4];
            a.x += x.x; a.y += x.y; a.z += x.z; a.w += x.w;
        }
        red[tid][0] = a.x; red[tid][1] = a.y; red[tid][2] = a.z; red[tid][3] = a.w;
    }
    __syncthreads();
    if (tid < 32) {
        float s0 = 0.f, s1 = 0.f, s2 = 0.f, s3 = 0.f;
#pragma unroll
        for (int r = 0; r < 16; ++r) {
            s0 += red[r * 32 + tid][0]; s1 += red[r * 32 + tid][1];
            s2 += red[r * 32 + tid][2]; s3 += red[r * 32 + tid][3];
        }
        const float inv = 1.0f / (float)TSEG;
        mv[tid * 4 + 0] = s0 * inv; mv[tid * 4 + 1] = s1 * inv;
        mv[tid * 4 + 2] = s2 * inv; mv[tid * 4 + 3] = s3 * inv;
    }
    __syncthreads();

    // ---------------- post chain (threads 0..127 own channel tid) ----------------
    const bool act = tid < DL;
    const float k0 = act ? mk[tid] : 0.f;
    const float v0 = act ? mv[tid] : 0.f;

    // write gate: sigmoid(LN(k0) @ wg_w + wg_b)
    float mean = blocksum(k0, sc, tid) * (1.f / DL);
    float xm   = act ? (k0 - mean) : 0.f;
    float var  = blocksum(xm * xm, sc, tid) * (1.f / DL);
    float rstd = 1.f / sqrtf(var + 1e-5f);
    float lnx  = act ? (xm * rstd * wg_ln_g[tid] + wg_ln_b[tid]) : 0.f;
    float dot  = blocksum(act ? lnx * wg_w[tid] : 0.f, sc, tid) + wg_b[0];
    float g    = 1.f / (1.f + expf(-dot));

    float k1 = k0 * g, v1 = v0 * g;

    // retention: softmax(LN(k1) @ rh_w + rh_b); scale = p0 + 0.5 p1
    mean = blocksum(k1, sc, tid) * (1.f / DL);
    xm   = act ? (k1 - mean) : 0.f;
    var  = blocksum(xm * xm, sc, tid) * (1.f / DL);
    rstd = 1.f / sqrtf(var + 1e-5f);
    lnx  = act ? (xm * rstd * rh_ln_g[tid] + rh_ln_b[tid]) : 0.f;
    float l0 = blocksum(act ? lnx * rh_w[0 * DL + tid] : 0.f, sc, tid) + rh_b[0];
    float l1 = blocksum(act ? lnx * rh_w[1 * DL + tid] : 0.f, sc, tid) + rh_b[1];
    float l2 = blocksum(act ? lnx * rh_w[2 * DL + tid] : 0.f, sc, tid) + rh_b[2];
    float mx = fmaxf(l0, fmaxf(l1, l2));
    float e0 = expf(l0 - mx), e1 = expf(l1 - mx), e2 = expf(l2 - mx);
    float scale = (e0 + 0.5f * e1) / (e0 + e1 + e2);

    float k2 = k1 * scale, v2 = v1 * scale;

    // post-k LN
    mean = blocksum(k2, sc, tid) * (1.f / DL);
    xm   = act ? (k2 - mean) : 0.f;
    var  = blocksum(xm * xm, sc, tid) * (1.f / DL);
    rstd = 1.f / sqrtf(var + 1e-5f);
    if (act) lnk[tid] = xm * rstd * pk_ln_g[tid] + pk_ln_b[tid];

    // post-v LN
    mean = blocksum(v2, sc, tid) * (1.f / DL);
    xm   = act ? (v2 - mean) : 0.f;
    var  = blocksum(xm * xm, sc, tid) * (1.f / DL);
    rstd = 1.f / sqrtf(var + 1e-5f);
    if (act) lnv[tid] = xm * rstd * pv_ln_g[tid] + pv_ln_b[tid];
    __syncthreads();

    // final 128x128 matmuls: threads 0..127 -> k_out row, 128..255 -> v_out row
    if (tid < 2 * DL) {
        const int  j   = tid & (DL - 1);
        const bool isv = tid >= DL;
        const float4* wr = (const float4*)((isv ? pv_w : pk_w) + j * DL);
        const float4* sr = (const float4*)(isv ? lnv : lnk);
        float acc = 0.f;
#pragma unroll
        for (int q = 0; q < DL / 4; ++q) {
            float4 w4 = wr[q];
            float4 x4 = sr[q];
            acc += w4.x * x4.x + w4.y * x4.y + w4.z * x4.z + w4.w * x4.w;
        }
        out[(isv ? vout_off : 0) + (long long)seg * DL + j] = acc;
    }
}

extern "C" void kernel_launch(void* const* d_in, const int* in_sizes, int n_in,
                              void* d_out, int out_size, void* d_ws, size_t ws_size,
                              hipStream_t stream) {
    const float* k_lat   = (const float*)d_in[0];
    const float* v_lat   = (const float*)d_in[1];
    const float* wg_ln_g = (const float*)d_in[2];
    const float* wg_ln_b = (const float*)d_in[3];
    const float* wg_w    = (const float*)d_in[4];
    const float* wg_b    = (const float*)d_in[5];
    const float* rh_ln_g = (const float*)d_in[6];
    const float* rh_ln_b = (const float*)d_in[7];
    const float* rh_w    = (const float*)d_in[8];
    const float* rh_b    = (const float*)d_in[9];
    const float* pk_ln_g = (const float*)d_in[10];
    const float* pk_ln_b = (const float*)d_in[11];
    const float* pk_w    = (const float*)d_in[12];
    const float* pv_ln_g = (const float*)d_in[13];
    const float* pv_ln_b = (const float*)d_in[14];
    const float* pv_w    = (const float*)d_in[15];

    const int n_seg = in_sizes[0] / (TSEG * DL);       // B*H*SLOTS = 1024
    const long long vout_off = (long long)out_size / 2; // k_out | v_out split

    ckv_fused<<<dim3(n_seg), dim3(NT), 0, stream>>>(
        k_lat, v_lat,
        wg_ln_g, wg_ln_b, wg_w, wg_b,
        rh_ln_g, rh_ln_b, rh_w, rh_b,
        pk_ln_g, pk_ln_b, pk_w,
        pv_ln_g, pv_ln_b, pv_w,
        (float*)d_out, vout_off);
}

// Round 2
// 171.464 us; speedup vs baseline: 1.3598x; 1.3598x over previous
//
#include <hip/hip_runtime.h>
#include <math.h>

#define NT 512      // threads per block (8 waves)
#define DL 128      // latent dim
#define TSEG 1024   // T / SLOTS = 8192 / 8

typedef float f32x4 __attribute__((ext_vector_type(4)));

// Block-wide sum of N values per thread (inactive threads pass 0).
// Results returned in x[0..N-1] to every thread.
template<int N>
__device__ __forceinline__ void blocksumN(float* x, float sc[][4], int tid) {
#pragma unroll
    for (int o = 1; o < 64; o <<= 1) {
#pragma unroll
        for (int i = 0; i < N; ++i) x[i] += __shfl_xor(x[i], o, 64);
    }
    __syncthreads();                 // WAR protection on sc
    if ((tid & 63) == 0) {
#pragma unroll
        for (int i = 0; i < N; ++i) sc[tid >> 6][i] = x[i];
    }
    __syncthreads();
#pragma unroll
    for (int i = 0; i < N; ++i) {
        float s = 0.f;
#pragma unroll
        for (int w = 0; w < NT / 64; ++w) s += sc[w][i];
        x[i] = s;
    }
}

extern "C" __global__ void __launch_bounds__(NT)
ckv_fused(const float* __restrict__ k_lat, const float* __restrict__ v_lat,
          const float* __restrict__ wg_ln_g, const float* __restrict__ wg_ln_b,
          const float* __restrict__ wg_w,    const float* __restrict__ wg_b,
          const float* __restrict__ rh_ln_g, const float* __restrict__ rh_ln_b,
          const float* __restrict__ rh_w,    const float* __restrict__ rh_b,
          const float* __restrict__ pk_ln_g, const float* __restrict__ pk_ln_b,
          const float* __restrict__ pk_w,
          const float* __restrict__ pv_ln_g, const float* __restrict__ pv_ln_b,
          const float* __restrict__ pv_w,
          float* __restrict__ out, long long vout_off)
{
    __shared__ float redk[NT][5];    // stride-5 pad: conflict-free combine
    __shared__ float redv[NT][5];
    __shared__ float mk[DL], mv[DL], lnk[DL], lnv[DL];
    __shared__ float sc[NT / 64][4];

    const int tid = threadIdx.x;
    const int seg = blockIdx.x;                       // 0 .. B*H*SLOTS-1
    const long long base4 = (long long)seg * (TSEG * DL / 4);  // float4 units

    const int col4 = tid & 31;   // float4 column within a 128-float row
    const int rl   = tid >> 5;   // row lane 0..15

    // ---------------- pool k and v together, unroll 2 ----------------
    {
        const f32x4* kp = (const f32x4*)k_lat + base4;
        const f32x4* vp = (const f32x4*)v_lat + base4;
        f32x4 ak0 = 0.f, ak1 = 0.f, av0 = 0.f, av1 = 0.f;
        for (int t = rl; t < TSEG; t += 32) {
            // 4 independent 16B loads in flight
            f32x4 xk0 = __builtin_nontemporal_load(kp + (t * 32 + col4));
            f32x4 xv0 = __builtin_nontemporal_load(vp + (t * 32 + col4));
            f32x4 xk1 = __builtin_nontemporal_load(kp + ((t + 16) * 32 + col4));
            f32x4 xv1 = __builtin_nontemporal_load(vp + ((t + 16) * 32 + col4));
            ak0 += xk0; av0 += xv0; ak1 += xk1; av1 += xv1;
        }
        f32x4 ak = ak0 + ak1, av = av0 + av1;
#pragma unroll
        for (int j = 0; j < 4; ++j) { redk[tid][j] = ak[j]; redv[tid][j] = av[j]; }
    }
    __syncthreads();
    if (tid < 64) {                      // one pass reduces both k and v
        const int   c   = tid & 31;
        const bool  isv = tid >= 32;
        const float (*rd)[5] = isv ? redv : redk;
        float*      dst      = isv ? mv : mk;
        float s0 = 0.f, s1 = 0.f, s2 = 0.f, s3 = 0.f;
#pragma unroll
        for (int r = 0; r < NT / 32; ++r) {
            s0 += rd[r * 32 + c][0]; s1 += rd[r * 32 + c][1];
            s2 += rd[r * 32 + c][2]; s3 += rd[r * 32 + c][3];
        }
        const float inv = 1.0f / (float)TSEG;
        dst[c * 4 + 0] = s0 * inv; dst[c * 4 + 1] = s1 * inv;
        dst[c * 4 + 2] = s2 * inv; dst[c * 4 + 3] = s3 * inv;
    }
    __syncthreads();

    // ---------------- post chain (threads 0..127 own channel tid) ----------------
    const bool act = tid < DL;
    const float k0 = act ? mk[tid] : 0.f;
    const float v0 = act ? mv[tid] : 0.f;

    // --- write gate: sigmoid(LN(k0) @ wg_w + wg_b) ---
    float s2v[2] = {k0, k0 * k0};
    blocksumN<2>(s2v, sc, tid);
    float mean = s2v[0] * (1.f / DL);
    float var  = s2v[1] * (1.f / DL) - mean * mean;
    float rstd = 1.f / sqrtf(var + 1e-5f);
    float lnx  = act ? ((k0 - mean) * rstd * wg_ln_g[tid] + wg_ln_b[tid]) : 0.f;
    float d1[1] = {act ? lnx * wg_w[tid] : 0.f};
    blocksumN<1>(d1, sc, tid);
    float g = 1.f / (1.f + expf(-(d1[0] + wg_b[0])));

    float k1 = k0 * g, v1 = v0 * g;

    // --- retention: softmax(LN(k1) @ rh_w + rh_b); scale = p0 + 0.5 p1 ---
    s2v[0] = k1; s2v[1] = k1 * k1;
    blocksumN<2>(s2v, sc, tid);
    mean = s2v[0] * (1.f / DL);
    var  = s2v[1] * (1.f / DL) - mean * mean;
    rstd = 1.f / sqrtf(var + 1e-5f);
    lnx  = act ? ((k1 - mean) * rstd * rh_ln_g[tid] + rh_ln_b[tid]) : 0.f;
    float d3[3];
    d3[0] = act ? lnx * rh_w[0 * DL + tid] : 0.f;
    d3[1] = act ? lnx * rh_w[1 * DL + tid] : 0.f;
    d3[2] = act ? lnx * rh_w[2 * DL + tid] : 0.f;
    blocksumN<3>(d3, sc, tid);
    float l0 = d3[0] + rh_b[0], l1 = d3[1] + rh_b[1], l2 = d3[2] + rh_b[2];
    float mx = fmaxf(l0, fmaxf(l1, l2));
    float e0 = expf(l0 - mx), e1 = expf(l1 - mx), e2 = expf(l2 - mx);
    float scale = (e0 + 0.5f * e1) / (e0 + e1 + e2);

    float k2 = k1 * scale, v2 = v1 * scale;

    // --- post-k / post-v LN, fused stats ---
    float s4[4] = {k2, k2 * k2, v2, v2 * v2};
    blocksumN<4>(s4, sc, tid);
    {
        float mk2 = s4[0] * (1.f / DL);
        float vk2 = s4[1] * (1.f / DL) - mk2 * mk2;
        float rk  = 1.f / sqrtf(vk2 + 1e-5f);
        float mv2 = s4[2] * (1.f / DL);
        float vv2 = s4[3] * (1.f / DL) - mv2 * mv2;
        float rv  = 1.f / sqrtf(vv2 + 1e-5f);
        if (act) {
            lnk[tid] = (k2 - mk2) * rk * pk_ln_g[tid] + pk_ln_b[tid];
            lnv[tid] = (v2 - mv2) * rv * pv_ln_g[tid] + pv_ln_b[tid];
        }
    }
    __syncthreads();

    // ---------------- final 128x128 matmuls ----------------
    if (tid < 2 * DL) {
        const int  j   = tid & (DL - 1);
        const bool isv = tid >= DL;
        const f32x4* wr = (const f32x4*)((isv ? pv_w : pk_w) + j * DL);
        const f32x4* sr = (const f32x4*)(isv ? lnv : lnk);
        float acc = 0.f;
#pragma unroll
        for (int q = 0; q < DL / 4; ++q) {
            f32x4 w4 = wr[q];
            f32x4 x4 = sr[q];
            acc += w4.x * x4.x + w4.y * x4.y + w4.z * x4.z + w4.w * x4.w;
        }
        out[(isv ? vout_off : 0) + (long long)seg * DL + j] = acc;
    }
}

extern "C" void kernel_launch(void* const* d_in, const int* in_sizes, int n_in,
                              void* d_out, int out_size, void* d_ws, size_t ws_size,
                              hipStream_t stream) {
    const float* k_lat   = (const float*)d_in[0];
    const float* v_lat   = (const float*)d_in[1];
    const float* wg_ln_g = (const float*)d_in[2];
    const float* wg_ln_b = (const float*)d_in[3];
    const float* wg_w    = (const float*)d_in[4];
    const float* wg_b    = (const float*)d_in[5];
    const float* rh_ln_g = (const float*)d_in[6];
    const float* rh_ln_b = (const float*)d_in[7];
    const float* rh_w    = (const float*)d_in[8];
    const float* rh_b    = (const float*)d_in[9];
    const float* pk_ln_g = (const float*)d_in[10];
    const float* pk_ln_b = (const float*)d_in[11];
    const float* pk_w    = (const float*)d_in[12];
    const float* pv_ln_g = (const float*)d_in[13];
    const float* pv_ln_b = (const float*)d_in[14];
    const float* pv_w    = (const float*)d_in[15];

    const int n_seg = in_sizes[0] / (TSEG * DL);        // B*H*SLOTS = 1024
    const long long vout_off = (long long)out_size / 2; // k_out | v_out split

    ckv_fused<<<dim3(n_seg), dim3(NT), 0, stream>>>(
        k_lat, v_lat,
        wg_ln_g, wg_ln_b, wg_w, wg_b,
        rh_ln_g, rh_ln_b, rh_w, rh_b,
        pk_ln_g, pk_ln_b, pk_w,
        pv_ln_g, pv_ln_b, pv_w,
        (float*)d_out, vout_off);
}